// Round 11
// baseline (61.997 us; speedup 1.0000x reference)
//
#include <hip/hip_runtime.h>
#include <hip/hip_fp16.h>

#define NN 50000
#define NE 800000
#define D  64
#define NBUK 256
#define CHUNK (NE / NBUK)   // 3125 exactly
#define FS 68               // feat LDS stride (pad 64 -> 68)

typedef float __attribute__((ext_vector_type(4))) f32x4;

// ---------------------------------------------------------------------------
// block-wide exclusive scan of one int per thread (256 threads = 4 waves).
__device__ inline int block_exscan(int val, int tid) {
    __shared__ int wsum[4];
    int lane = tid & 63, w = tid >> 6;
    int v = val;
    #pragma unroll
    for (int d = 1; d < 64; d <<= 1) {
        int t = __shfl_up(v, d);
        if (lane >= d) v += t;
    }
    if (lane == 63) wsum[w] = v;
    __syncthreads();
    int base = 0;
    #pragma unroll
    for (int i = 0; i < 4; ++i) base += (i < w) ? wsum[i] : 0;
    __syncthreads();
    return base + v - val;   // exclusive
}

// ---------------------------------------------------------------------------
// pass A: per-block LDS histogram over buckets (col>>8). H is bucket-major.
__global__ __launch_bounds__(256) void k_hist(const int* __restrict__ col,
                                              int* __restrict__ H) {
    __shared__ int h[NBUK];
    const int tid = threadIdx.x, blk = blockIdx.x;
    h[tid] = 0;
    __syncthreads();
    const int base = blk * CHUNK;
    for (int i = tid; i < CHUNK; i += 256)
        atomicAdd(&h[col[base + i] >> 8], 1);
    __syncthreads();
    H[tid * NBUK + blk] = h[tid];
}

// pass B: scan H in place. Block j covers bucket j; bsum[j] = bucket total.
__global__ __launch_bounds__(256) void k_scanA(int* __restrict__ H,
                                               int* __restrict__ bsum) {
    const int tid = threadIdx.x, blk = blockIdx.x;
    const int i = blk * 256 + tid;
    int val = H[i];
    int ex = block_exscan(val, tid);
    H[i] = ex;
    if (tid == 255) bsum[blk] = ex + val;
}

// pass C: scatter edges into bucket segments as packed (row | (col&255)<<16)
__global__ __launch_bounds__(256) void k_bucket(const int* __restrict__ row,
                                                const int* __restrict__ col,
                                                const int* __restrict__ H,
                                                const int* __restrict__ bsum,
                                                unsigned int* __restrict__ packed) {
    __shared__ int base_l[NBUK];
    __shared__ int rank[NBUK];
    const int tid = threadIdx.x, blk = blockIdx.x;
    int ex = block_exscan(bsum[tid], tid);      // global bucket base
    base_l[tid] = ex + H[tid * NBUK + blk];     // + this block's chunk offset
    rank[tid] = 0;
    __syncthreads();
    const int base = blk * CHUNK;
    for (int i = tid; i < CHUNK; i += 256) {
        int c = col[base + i], r = row[base + i];
        int bk = c >> 8;
        int rk = atomicAdd(&rank[bk], 1);
        packed[base_l[bk] + rk] =
            (unsigned)(r & 0xFFFF) | ((unsigned)(c & 0xFF) << 16);
    }
}

// pass D: per-bucket CSR finalize: off/cnt per node + csr ushort rows.
__global__ __launch_bounds__(256) void k_csr(const unsigned int* __restrict__ packed,
                                             const int* __restrict__ bsum,
                                             int* __restrict__ off,
                                             int* __restrict__ cnt,
                                             unsigned short* __restrict__ csr) {
    __shared__ int exs[NBUK];
    __shared__ int ncnt[NBUK];
    __shared__ int nbase[NBUK];
    __shared__ int rk2[NBUK];
    const int tid = threadIdx.x, b = blockIdx.x;
    int ex = block_exscan(bsum[tid], tid);
    exs[tid] = ex;
    ncnt[tid] = 0;
    rk2[tid] = 0;
    __syncthreads();
    const int start = exs[b];
    const int size  = bsum[b];
    for (int i = tid; i < size; i += 256)
        atomicAdd(&ncnt[(packed[start + i] >> 16) & 0xFF], 1);
    __syncthreads();
    int v2  = ncnt[tid];
    int ex2 = block_exscan(v2, tid);
    const int node = b * NBUK + tid;
    off[node] = start + ex2;
    cnt[node] = v2;
    nbase[tid] = start + ex2;
    __syncthreads();
    for (int i = tid; i < size; i += 256) {
        unsigned u = packed[start + i];
        int ln = (u >> 16) & 0xFF;
        int rk = atomicAdd(&rk2[ln], 1);
        csr[nbase[ln] + rk] = (unsigned short)(u & 0xFFFF);
    }
}

// ---------------------------------------------------------------------------
// k_gemm: y{0,1}[r][d] = fp16( (feat[r] . W[:,d]) * rsqrt(cnt[r]+1) )
// column-split output: y0 = dims 0..31, y1 = dims 32..63 (each [NN,32] fp16)
__global__ __launch_bounds__(256) void k_gemm(const float* __restrict__ feat,
                                              const float* __restrict__ W,
                                              const int* __restrict__ cnt,
                                              __half* __restrict__ y0,
                                              __half* __restrict__ y1) {
    __shared__ float feat_lds[64 * FS];
    __shared__ float W_lds[D * D];

    const int tid   = threadIdx.x;
    const int rbase = blockIdx.x * 64;

    {
        const float4* W4  = reinterpret_cast<const float4*>(W);
        float4*       Wl4 = reinterpret_cast<float4*>(W_lds);
        for (int i = tid; i < D * D / 4; i += 256) Wl4[i] = W4[i];
    }
    {
        const int k0 = (tid & 15) * 4;
        #pragma unroll
        for (int it = 0; it < 4; ++it) {
            int r  = it * 16 + (tid >> 4);
            int gr = rbase + r;
            float4 v = make_float4(0.f, 0.f, 0.f, 0.f);
            if (gr < NN) v = *reinterpret_cast<const float4*>(&feat[gr * D + k0]);
            *reinterpret_cast<float4*>(&feat_lds[r * FS + k0]) = v;
        }
    }
    __syncthreads();

    const int tx = tid & 15;
    const int ty = tid >> 4;

    float acc[4][4] = {};

    #pragma unroll 8
    for (int k = 0; k < D; ++k) {
        float4 w = *reinterpret_cast<const float4*>(&W_lds[k * D + tx * 4]);
        float f0 = feat_lds[(ty * 4 + 0) * FS + k];
        float f1 = feat_lds[(ty * 4 + 1) * FS + k];
        float f2 = feat_lds[(ty * 4 + 2) * FS + k];
        float f3 = feat_lds[(ty * 4 + 3) * FS + k];
        acc[0][0] = fmaf(f0, w.x, acc[0][0]); acc[0][1] = fmaf(f0, w.y, acc[0][1]);
        acc[0][2] = fmaf(f0, w.z, acc[0][2]); acc[0][3] = fmaf(f0, w.w, acc[0][3]);
        acc[1][0] = fmaf(f1, w.x, acc[1][0]); acc[1][1] = fmaf(f1, w.y, acc[1][1]);
        acc[1][2] = fmaf(f1, w.z, acc[1][2]); acc[1][3] = fmaf(f1, w.w, acc[1][3]);
        acc[2][0] = fmaf(f2, w.x, acc[2][0]); acc[2][1] = fmaf(f2, w.y, acc[2][1]);
        acc[2][2] = fmaf(f2, w.z, acc[2][2]); acc[2][3] = fmaf(f2, w.w, acc[2][3]);
        acc[3][0] = fmaf(f3, w.x, acc[3][0]); acc[3][1] = fmaf(f3, w.y, acc[3][1]);
        acc[3][2] = fmaf(f3, w.z, acc[3][2]); acc[3][3] = fmaf(f3, w.w, acc[3][3]);
    }

    const int d0 = tx * 4;
    #pragma unroll
    for (int i = 0; i < 4; ++i) {
        int gr = rbase + ty * 4 + i;
        if (gr < NN) {
            float s = rsqrtf((float)cnt[gr] + 1.0f);
            __half2 h0 = __floats2half2_rn(acc[i][0] * s, acc[i][1] * s);
            __half2 h1 = __floats2half2_rn(acc[i][2] * s, acc[i][3] * s);
            union { __half2 h[2]; uint2 u; } p;
            p.h[0] = h0; p.h[1] = h1;
            __half* dst = (d0 < 32) ? &y0[gr * 32 + d0] : &y1[gr * 32 + (d0 - 32)];
            *reinterpret_cast<uint2*>(dst) = p.u;
        }
    }
}

// ---------------------------------------------------------------------------
// k_agg4: R10's winning structure + XCD parity split for L2 residency.
//  - 4-lane group per (node,half); 16 groups/wave; lane l4 owns 16B of the
//    64B half-row -> NO cross-lane reduction (same as R10).
//  - half = blockIdx.x & 1: round-robin dispatch gives even XCDs half 0,
//    odd XCDs half 1 -> per-XCD resident set = one 3.2 MB y-half < 4 MB L2.
//  - pre[8] statically-indexed prefetch of 32 edge ids; 8 row-gathers issued
//    unconditionally per block before accumulating (mask-FMA) -> 8 in flight.
//  - shfl guards wave-uniform (maxn) -> all 64 lanes active at every shfl.
//  - NT loads for csr/off/cnt, NT stores for out: streams don't evict y.
__global__ __launch_bounds__(256) void k_agg4(const unsigned short* __restrict__ csr,
                                              const int* __restrict__ off,
                                              const int* __restrict__ cnt,
                                              const __half* __restrict__ y0,
                                              const __half* __restrict__ y1,
                                              const float* __restrict__ b,
                                              float* __restrict__ out) {
    const int lane = threadIdx.x & 63;
    const int g    = lane >> 2;        // group 0..15 = node slot within wave
    const int l4   = lane & 3;         // 16B block within the 64B half-row
    const int half = blockIdx.x & 1;
    const int wave = (blockIdx.x >> 1) * 4 + (threadIdx.x >> 6);
    const int c    = wave * 16 + g;
    const bool valid = (c < NN);

    const __half* yh = half ? y1 : y0;
    const uint4* y16 = reinterpret_cast<const uint4*>(yh);   // row = 4 x uint4

    const int s = valid ? __builtin_nontemporal_load(&off[c]) : 0;
    const int n = valid ? __builtin_nontemporal_load(&cnt[c]) : 0;

    // wave max of n (n uniform within each 4-lane group)
    int maxn = n;
    #pragma unroll
    for (int m = 4; m <= 32; m <<= 1) maxn = max(maxn, __shfl_xor(maxn, m));

    // prefetch up to 32 neighbor ids per group: pre[k] holds edge l4 + 4k
    int pre[8];
    #pragma unroll
    for (int k = 0; k < 8; ++k)
        pre[k] = (l4 + 4 * k < n)
               ? (int)__builtin_nontemporal_load(&csr[s + l4 + 4 * k]) : 0;

    float acc[8] = {0.f, 0.f, 0.f, 0.f, 0.f, 0.f, 0.f, 0.f};

    auto addm = [&](uint4 u, float m) {
        const __half2* h = reinterpret_cast<const __half2*>(&u);
        float2 f0 = __half22float2(h[0]);
        float2 f1 = __half22float2(h[1]);
        float2 f2 = __half22float2(h[2]);
        float2 f3 = __half22float2(h[3]);
        acc[0] = fmaf(m, f0.x, acc[0]); acc[1] = fmaf(m, f0.y, acc[1]);
        acc[2] = fmaf(m, f1.x, acc[2]); acc[3] = fmaf(m, f1.y, acc[3]);
        acc[4] = fmaf(m, f2.x, acc[4]); acc[5] = fmaf(m, f2.y, acc[5]);
        acc[6] = fmaf(m, f3.x, acc[6]); acc[7] = fmaf(m, f3.y, acc[7]);
    };

    // self-loop (safe index when invalid, masked to 0)
    {
        int cs = valid ? c : 0;
        addm(y16[cs * 4 + l4], valid ? 1.0f : 0.0f);
    }

    const int srcb = lane & 60;   // first lane of this group

    #pragma unroll
    for (int w = 0; w < 4; ++w) {
        if (w * 8 < maxn) {                            // wave-uniform guard
            uint4 u[8];
            float msk[8];
            #pragma unroll
            for (int e = 0; e < 8; ++e) {
                const int idx = w * 8 + e;             // compile-time constant
                int r = __shfl(pre[idx >> 2], srcb + (idx & 3));  // all lanes active
                u[e] = y16[r * 4 + l4];                // unconditional -> in flight
                msk[e] = (idx < n) ? 1.0f : 0.0f;
            }
            #pragma unroll
            for (int e = 0; e < 8; ++e) addm(u[e], msk[e]);
        }
    }

    // rare tail (deg > 32): group-divergent, no shfl -> safe
    for (int i = 32; i < n; ++i) {
        int r = (int)csr[s + i];
        addm(y16[r * 4 + l4], 1.0f);
    }

    if (valid) {
        float sc = rsqrtf((float)n + 1.0f);
        const float4* b4 = reinterpret_cast<const float4*>(b);
        float4 bb0 = b4[half * 8 + l4 * 2], bb1 = b4[half * 8 + l4 * 2 + 1];
        f32x4 o0, o1;
        o0.x = acc[0] * sc + bb0.x;  o0.y = acc[1] * sc + bb0.y;
        o0.z = acc[2] * sc + bb0.z;  o0.w = acc[3] * sc + bb0.w;
        o1.x = acc[4] * sc + bb1.x;  o1.y = acc[5] * sc + bb1.y;
        o1.z = acc[6] * sc + bb1.z;  o1.w = acc[7] * sc + bb1.w;
        f32x4* out4 = reinterpret_cast<f32x4*>(out);
        __builtin_nontemporal_store(o0, &out4[c * 16 + half * 8 + l4 * 2]);
        __builtin_nontemporal_store(o1, &out4[c * 16 + half * 8 + l4 * 2 + 1]);
    }
}

// ---------------------------------------------------------------------------
extern "C" void kernel_launch(void* const* d_in, const int* in_sizes, int n_in,
                              void* d_out, int out_size, void* d_ws, size_t ws_size,
                              hipStream_t stream) {
    const float* feat = (const float*)d_in[0];   // [NN, D]
    const float* W    = (const float*)d_in[1];   // [D, D]
    const float* b    = (const float*)d_in[2];   // [D]
    const int*   ei   = (const int*)d_in[3];     // [2, NE]
    const int*   row  = ei;                      // sources
    const int*   col  = ei + NE;                 // targets

    float* out = (float*)d_out;                  // [NN, D]

    // workspace layout (~12 MB)
    int*            H      = (int*)d_ws;                      // [65536]
    int*            bsum   = H + 65536;                       // [256] (pad 1024)
    int*            cnt    = bsum + 1024;                     // [65536]
    int*            off    = cnt + 65536;                     // [65536]
    unsigned int*   packed = (unsigned int*)(off + 65536);    // [NE]
    unsigned short* csr    = (unsigned short*)(packed + NE);  // [NE]
    __half*         y0     = (__half*)(csr + NE);             // [NN*32]
    __half*         y1     = y0 + NN * 32;                    // [NN*32]

    k_hist  <<<NBUK, 256, 0, stream>>>(col, H);
    k_scanA <<<NBUK, 256, 0, stream>>>(H, bsum);
    k_bucket<<<NBUK, 256, 0, stream>>>(row, col, H, bsum, packed);
    k_csr   <<<NBUK, 256, 0, stream>>>(packed, bsum, off, cnt, csr);
    k_gemm  <<<(NN + 63) / 64, 256, 0, stream>>>(feat, W, cnt, y0, y1);
    // grid: 2 halves x ceil(NN/64) node-blocks; parity -> XCD-resident y-half
    k_agg4  <<<2 * ((NN + 63) / 64), 256, 0, stream>>>(csr, off, cnt, y0, y1, b, out);
}

// Round 12
// 59.360 us; speedup vs baseline: 1.0444x; 1.0444x over previous
//
#include <hip/hip_runtime.h>
#include <hip/hip_fp16.h>

#define NN 50000
#define NE 800000
#define D  64
#define NBUK  256
#define NBLKS 250            // sort chunks: 250 x 3200 = 800000 exactly
#define CHUNK2 3200          // multiple of 4 -> uint4 edge reads
#define FS 68                // feat LDS stride (pad 64 -> 68)

typedef float __attribute__((ext_vector_type(4))) f32x4;

// ---------------------------------------------------------------------------
// block-wide exclusive scan of one int per thread (256 threads = 4 waves).
__device__ inline int block_exscan(int val, int tid) {
    __shared__ int wsum[4];
    int lane = tid & 63, w = tid >> 6;
    int v = val;
    #pragma unroll
    for (int d = 1; d < 64; d <<= 1) {
        int t = __shfl_up(v, d);
        if (lane >= d) v += t;
    }
    if (lane == 63) wsum[w] = v;
    __syncthreads();
    int base = 0;
    #pragma unroll
    for (int i = 0; i < 4; ++i) base += (i < w) ? wsum[i] : 0;
    __syncthreads();
    return base + v - val;   // exclusive
}

// ---------------------------------------------------------------------------
// pass A: per-block LDS histogram over buckets (col>>8); uint4 edge reads.
// H layout: H[bucket*256 + blk], blk < NBLKS.
__global__ __launch_bounds__(256) void k_hist(const int* __restrict__ col,
                                              int* __restrict__ H) {
    __shared__ int h[NBUK];
    const int tid = threadIdx.x, blk = blockIdx.x;
    h[tid] = 0;
    __syncthreads();
    const uint4* col4 = reinterpret_cast<const uint4*>(col + blk * CHUNK2);
    for (int i = tid; i < CHUNK2 / 4; i += 256) {
        uint4 v = col4[i];
        atomicAdd(&h[v.x >> 8], 1);
        atomicAdd(&h[v.y >> 8], 1);
        atomicAdd(&h[v.z >> 8], 1);
        atomicAdd(&h[v.w >> 8], 1);
    }
    __syncthreads();
    H[tid * 256 + blk] = h[tid];
}

// pass B: scan H in place. Block j covers bucket j; bsum[j] = bucket total.
// (entries blk >= NBLKS read as 0 -> no zeroing of poisoned ws needed)
__global__ __launch_bounds__(256) void k_scanA(int* __restrict__ H,
                                               int* __restrict__ bsum) {
    const int tid = threadIdx.x, blk = blockIdx.x;
    const int i = blk * 256 + tid;
    int val = (tid < NBLKS) ? H[i] : 0;
    int ex = block_exscan(val, tid);
    if (tid < NBLKS) H[i] = ex;
    if (tid == 255) bsum[blk] = ex + val;
}

// pass C: scatter edges into bucket segments as packed (row | (col&255)<<16);
// uint4 edge reads.
__global__ __launch_bounds__(256) void k_bucket(const int* __restrict__ row,
                                                const int* __restrict__ col,
                                                const int* __restrict__ H,
                                                const int* __restrict__ bsum,
                                                unsigned int* __restrict__ packed) {
    __shared__ int base_l[NBUK];
    __shared__ int rank[NBUK];
    const int tid = threadIdx.x, blk = blockIdx.x;
    int ex = block_exscan(bsum[tid], tid);      // global bucket base
    base_l[tid] = ex + H[tid * 256 + blk];      // + this block's chunk offset
    rank[tid] = 0;
    __syncthreads();
    const uint4* col4 = reinterpret_cast<const uint4*>(col + blk * CHUNK2);
    const uint4* row4 = reinterpret_cast<const uint4*>(row + blk * CHUNK2);
    for (int i = tid; i < CHUNK2 / 4; i += 256) {
        uint4 c4 = col4[i];
        uint4 r4 = row4[i];
        #pragma unroll
        for (int e = 0; e < 4; ++e) {
            unsigned c = (e == 0) ? c4.x : (e == 1) ? c4.y : (e == 2) ? c4.z : c4.w;
            unsigned r = (e == 0) ? r4.x : (e == 1) ? r4.y : (e == 2) ? r4.z : r4.w;
            int bk = c >> 8;
            int rk = atomicAdd(&rank[bk], 1);
            packed[base_l[bk] + rk] = (r & 0xFFFF) | ((c & 0xFF) << 16);
        }
    }
}

// pass D: per-bucket CSR finalize: off/cnt per node + csr ushort rows.
__global__ __launch_bounds__(256) void k_csr(const unsigned int* __restrict__ packed,
                                             const int* __restrict__ bsum,
                                             int* __restrict__ off,
                                             int* __restrict__ cnt,
                                             unsigned short* __restrict__ csr) {
    __shared__ int exs[NBUK];
    __shared__ int ncnt[NBUK];
    __shared__ int nbase[NBUK];
    __shared__ int rk2[NBUK];
    const int tid = threadIdx.x, b = blockIdx.x;
    int ex = block_exscan(bsum[tid], tid);
    exs[tid] = ex;
    ncnt[tid] = 0;
    rk2[tid] = 0;
    __syncthreads();
    const int start = exs[b];
    const int size  = bsum[b];
    for (int i = tid; i < size; i += 256)
        atomicAdd(&ncnt[(packed[start + i] >> 16) & 0xFF], 1);
    __syncthreads();
    int v2  = ncnt[tid];
    int ex2 = block_exscan(v2, tid);
    const int node = b * NBUK + tid;
    off[node] = start + ex2;
    cnt[node] = v2;
    nbase[tid] = start + ex2;
    __syncthreads();
    for (int i = tid; i < size; i += 256) {
        unsigned u = packed[start + i];
        int ln = (u >> 16) & 0xFF;
        int rk = atomicAdd(&rk2[ln], 1);
        csr[nbase[ln] + rk] = (unsigned short)(u & 0xFFFF);
    }
}

// ---------------------------------------------------------------------------
// k_gemm: y[r][d] = fp16( (feat[r] . W[:,d]) * rsqrt(cnt[r]+1) )
__global__ __launch_bounds__(256) void k_gemm(const float* __restrict__ feat,
                                              const float* __restrict__ W,
                                              const int* __restrict__ cnt,
                                              __half* __restrict__ y) {
    __shared__ float feat_lds[64 * FS];
    __shared__ float W_lds[D * D];

    const int tid   = threadIdx.x;
    const int rbase = blockIdx.x * 64;

    {
        const float4* W4  = reinterpret_cast<const float4*>(W);
        float4*       Wl4 = reinterpret_cast<float4*>(W_lds);
        for (int i = tid; i < D * D / 4; i += 256) Wl4[i] = W4[i];
    }
    {
        const int k0 = (tid & 15) * 4;
        #pragma unroll
        for (int it = 0; it < 4; ++it) {
            int r  = it * 16 + (tid >> 4);
            int gr = rbase + r;
            float4 v = make_float4(0.f, 0.f, 0.f, 0.f);
            if (gr < NN) v = *reinterpret_cast<const float4*>(&feat[gr * D + k0]);
            *reinterpret_cast<float4*>(&feat_lds[r * FS + k0]) = v;
        }
    }
    __syncthreads();

    const int tx = tid & 15;
    const int ty = tid >> 4;

    float acc[4][4] = {};

    #pragma unroll 8
    for (int k = 0; k < D; ++k) {
        float4 w = *reinterpret_cast<const float4*>(&W_lds[k * D + tx * 4]);
        float f0 = feat_lds[(ty * 4 + 0) * FS + k];
        float f1 = feat_lds[(ty * 4 + 1) * FS + k];
        float f2 = feat_lds[(ty * 4 + 2) * FS + k];
        float f3 = feat_lds[(ty * 4 + 3) * FS + k];
        acc[0][0] = fmaf(f0, w.x, acc[0][0]); acc[0][1] = fmaf(f0, w.y, acc[0][1]);
        acc[0][2] = fmaf(f0, w.z, acc[0][2]); acc[0][3] = fmaf(f0, w.w, acc[0][3]);
        acc[1][0] = fmaf(f1, w.x, acc[1][0]); acc[1][1] = fmaf(f1, w.y, acc[1][1]);
        acc[1][2] = fmaf(f1, w.z, acc[1][2]); acc[1][3] = fmaf(f1, w.w, acc[1][3]);
        acc[2][0] = fmaf(f2, w.x, acc[2][0]); acc[2][1] = fmaf(f2, w.y, acc[2][1]);
        acc[2][2] = fmaf(f2, w.z, acc[2][2]); acc[2][3] = fmaf(f2, w.w, acc[2][3]);
        acc[3][0] = fmaf(f3, w.x, acc[3][0]); acc[3][1] = fmaf(f3, w.y, acc[3][1]);
        acc[3][2] = fmaf(f3, w.z, acc[3][2]); acc[3][3] = fmaf(f3, w.w, acc[3][3]);
    }

    #pragma unroll
    for (int i = 0; i < 4; ++i) {
        int gr = rbase + ty * 4 + i;
        if (gr < NN) {
            float s = rsqrtf((float)cnt[gr] + 1.0f);
            __half2 h0 = __floats2half2_rn(acc[i][0] * s, acc[i][1] * s);
            __half2 h1 = __floats2half2_rn(acc[i][2] * s, acc[i][3] * s);
            union { __half2 h[2]; uint2 u; } p;
            p.h[0] = h0; p.h[1] = h1;
            *reinterpret_cast<uint2*>(&y[gr * D + tx * 4]) = p.u;
        }
    }
}

// ---------------------------------------------------------------------------
// k_agg16: R10's winning structure with 16-edge gather blocks.
//  - 8-lane group per node, 8 nodes/wave, lane owns 8 dims (no reduction).
//  - pre[4] holds 32 edge ids; per 16-edge block all 16 row-gathers issue
//    unconditionally (safe index 0 when OOB) before mask-FMA accumulation
//    -> 16 loads in flight, 2 drain points per wave (was 4).
//  - shfl guards wave-uniform (maxn) -> all 64 lanes active at every shfl.
__global__ __launch_bounds__(256) void k_agg16(const unsigned short* __restrict__ csr,
                                               const int* __restrict__ off,
                                               const int* __restrict__ cnt,
                                               const __half* __restrict__ y,
                                               const float* __restrict__ b,
                                               float* __restrict__ out) {
    const int lane = threadIdx.x & 63;
    const int g    = lane >> 3;        // group 0..7 = node slot within wave
    const int l8   = lane & 7;         // dim block within the node's row
    const int wave = blockIdx.x * 4 + (threadIdx.x >> 6);
    const int c    = wave * 8 + g;
    const bool valid = (c < NN);

    const uint4* y16 = reinterpret_cast<const uint4*>(y);

    const int s = valid ? off[c] : 0;
    const int n = valid ? cnt[c] : 0;   // group-uniform

    // wave max of n
    int maxn = n;
    maxn = max(maxn, __shfl_xor(maxn, 8));
    maxn = max(maxn, __shfl_xor(maxn, 16));
    maxn = max(maxn, __shfl_xor(maxn, 32));

    // prefetch up to 32 neighbor ids per group (pre[k] = edge l8 + 8k)
    int pre0 = (l8      < n) ? (int)csr[s + l8     ] : 0;
    int pre1 = (l8 + 8  < n) ? (int)csr[s + l8 + 8 ] : 0;
    int pre2 = (l8 + 16 < n) ? (int)csr[s + l8 + 16] : 0;
    int pre3 = (l8 + 24 < n) ? (int)csr[s + l8 + 24] : 0;

    float acc[8] = {0.f, 0.f, 0.f, 0.f, 0.f, 0.f, 0.f, 0.f};

    auto addm = [&](uint4 u, float m) {
        const __half2* h = reinterpret_cast<const __half2*>(&u);
        float2 f0 = __half22float2(h[0]);
        float2 f1 = __half22float2(h[1]);
        float2 f2 = __half22float2(h[2]);
        float2 f3 = __half22float2(h[3]);
        acc[0] = fmaf(m, f0.x, acc[0]); acc[1] = fmaf(m, f0.y, acc[1]);
        acc[2] = fmaf(m, f1.x, acc[2]); acc[3] = fmaf(m, f1.y, acc[3]);
        acc[4] = fmaf(m, f2.x, acc[4]); acc[5] = fmaf(m, f2.y, acc[5]);
        acc[6] = fmaf(m, f3.x, acc[6]); acc[7] = fmaf(m, f3.y, acc[7]);
    };

    // self-loop (safe index when invalid, masked to 0)
    {
        int cs = valid ? c : 0;
        addm(y16[cs * 8 + l8], valid ? 1.0f : 0.0f);
    }

    const int srcb = lane & 56;   // first lane of this group

    // block 0: edges 0..15 (maxn >= 1 whenever any work exists; guard anyway)
    if (maxn > 0) {                                  // wave-uniform
        uint4 u[16];
        float msk[16];
        #pragma unroll
        for (int e = 0; e < 16; ++e) {
            int r = __shfl((e < 8) ? pre0 : pre1, srcb + (e & 7));
            u[e] = y16[r * 8 + l8];                  // unconditional -> in flight
            msk[e] = (e < n) ? 1.0f : 0.0f;
        }
        #pragma unroll
        for (int e = 0; e < 16; ++e) addm(u[e], msk[e]);
    }
    // block 1: edges 16..31
    if (maxn > 16) {                                 // wave-uniform
        uint4 u[16];
        float msk[16];
        #pragma unroll
        for (int e = 0; e < 16; ++e) {
            int r = __shfl((e < 8) ? pre2 : pre3, srcb + (e & 7));
            u[e] = y16[r * 8 + l8];
            msk[e] = (16 + e < n) ? 1.0f : 0.0f;
        }
        #pragma unroll
        for (int e = 0; e < 16; ++e) addm(u[e], msk[e]);
    }

    // rare tail (deg > 32): group-divergent, no shfl -> safe
    for (int i = 32; i < n; ++i) {
        int r = (int)csr[s + i];
        addm(y16[r * 8 + l8], 1.0f);
    }

    if (valid) {
        float sc = rsqrtf((float)n + 1.0f);
        const float4* b4 = reinterpret_cast<const float4*>(b);
        float4 bb0 = b4[l8 * 2], bb1 = b4[l8 * 2 + 1];
        f32x4 o0, o1;
        o0.x = acc[0] * sc + bb0.x;  o0.y = acc[1] * sc + bb0.y;
        o0.z = acc[2] * sc + bb0.z;  o0.w = acc[3] * sc + bb0.w;
        o1.x = acc[4] * sc + bb1.x;  o1.y = acc[5] * sc + bb1.y;
        o1.z = acc[6] * sc + bb1.z;  o1.w = acc[7] * sc + bb1.w;
        f32x4* out4 = reinterpret_cast<f32x4*>(out);
        __builtin_nontemporal_store(o0, &out4[c * 16 + l8 * 2]);
        __builtin_nontemporal_store(o1, &out4[c * 16 + l8 * 2 + 1]);
    }
}

// ---------------------------------------------------------------------------
extern "C" void kernel_launch(void* const* d_in, const int* in_sizes, int n_in,
                              void* d_out, int out_size, void* d_ws, size_t ws_size,
                              hipStream_t stream) {
    const float* feat = (const float*)d_in[0];   // [NN, D]
    const float* W    = (const float*)d_in[1];   // [D, D]
    const float* b    = (const float*)d_in[2];   // [D]
    const int*   ei   = (const int*)d_in[3];     // [2, NE]
    const int*   row  = ei;                      // sources
    const int*   col  = ei + NE;                 // targets

    float* out = (float*)d_out;                  // [NN, D]

    // workspace layout (~12 MB)
    int*            H      = (int*)d_ws;                      // [65536]
    int*            bsum   = H + 65536;                       // [256] (pad 1024)
    int*            cnt    = bsum + 1024;                     // [65536]
    int*            off    = cnt + 65536;                     // [65536]
    unsigned int*   packed = (unsigned int*)(off + 65536);    // [NE]
    unsigned short* csr    = (unsigned short*)(packed + NE);  // [NE]
    __half*         y      = (__half*)(csr + NE);             // [NN*D], 16B-aligned

    k_hist  <<<NBLKS, 256, 0, stream>>>(col, H);
    k_scanA <<<NBUK,  256, 0, stream>>>(H, bsum);
    k_bucket<<<NBLKS, 256, 0, stream>>>(row, col, H, bsum, packed);
    k_csr   <<<NBUK,  256, 0, stream>>>(packed, bsum, off, cnt, csr);
    k_gemm  <<<(NN + 63) / 64, 256, 0, stream>>>(feat, W, cnt, y);
    k_agg16 <<<(NN + 31) / 32, 256, 0, stream>>>(csr, off, cnt, y, b, out);
}

// Round 13
// 57.876 us; speedup vs baseline: 1.0712x; 1.0256x over previous
//
#include <hip/hip_runtime.h>
#include <hip/hip_fp16.h>

#define NN 50000
#define NE 800000
#define D  64
#define NBUK  256
#define NBLKS 500            // sort chunks: 500 x 1600 = 800000 exactly
#define CHUNK2 1600          // multiple of 4 -> uint4 edge reads
#define HSTR  512            // H row stride (500 used, padded)
#define FS 68                // feat LDS stride (pad 64 -> 68)

typedef float __attribute__((ext_vector_type(4))) f32x4;

// ---------------------------------------------------------------------------
// block-wide exclusive scan of one int per thread (256 threads = 4 waves).
__device__ inline int block_exscan(int val, int tid) {
    __shared__ int wsum[4];
    int lane = tid & 63, w = tid >> 6;
    int v = val;
    #pragma unroll
    for (int d = 1; d < 64; d <<= 1) {
        int t = __shfl_up(v, d);
        if (lane >= d) v += t;
    }
    if (lane == 63) wsum[w] = v;
    __syncthreads();
    int base = 0;
    #pragma unroll
    for (int i = 0; i < 4; ++i) base += (i < w) ? wsum[i] : 0;
    __syncthreads();
    return base + v - val;   // exclusive
}

// ---------------------------------------------------------------------------
// pass A: per-block LDS histogram over buckets (col>>8); uint4 edge reads.
// H layout: H[bucket*HSTR + blk], blk < NBLKS. 500 blocks ~ 2/CU.
__global__ __launch_bounds__(256) void k_hist(const int* __restrict__ col,
                                              int* __restrict__ H) {
    __shared__ int h[NBUK];
    const int tid = threadIdx.x, blk = blockIdx.x;
    h[tid] = 0;
    __syncthreads();
    const uint4* col4 = reinterpret_cast<const uint4*>(col + blk * CHUNK2);
    for (int i = tid; i < CHUNK2 / 4; i += 256) {
        uint4 v = col4[i];
        atomicAdd(&h[v.x >> 8], 1);
        atomicAdd(&h[v.y >> 8], 1);
        atomicAdd(&h[v.z >> 8], 1);
        atomicAdd(&h[v.w >> 8], 1);
    }
    __syncthreads();
    H[tid * HSTR + blk] = h[tid];
}

// pass B: per-bucket exclusive scan over the 500 block entries.
// Block j = bucket j; thread t<250 owns entries {2t, 2t+1}; bsum[j] = total.
__global__ __launch_bounds__(256) void k_scanA(int* __restrict__ H,
                                               int* __restrict__ bsum) {
    const int tid = threadIdx.x, bkt = blockIdx.x;
    int* Hb = H + bkt * HSTR;
    int v0 = 0, v1 = 0;
    if (tid < 250) { v0 = Hb[2 * tid]; v1 = Hb[2 * tid + 1]; }
    int sum = v0 + v1;
    int ex = block_exscan(sum, tid);
    if (tid < 250) { Hb[2 * tid] = ex; Hb[2 * tid + 1] = ex + v0; }
    if (tid == 255) bsum[bkt] = ex;   // tid 255 has sum=0 -> ex == grand total
}

// pass C: scatter edges into bucket segments as packed (row | (col&255)<<16);
// uint4 edge reads.
__global__ __launch_bounds__(256) void k_bucket(const int* __restrict__ row,
                                                const int* __restrict__ col,
                                                const int* __restrict__ H,
                                                const int* __restrict__ bsum,
                                                unsigned int* __restrict__ packed) {
    __shared__ int base_l[NBUK];
    __shared__ int rank[NBUK];
    const int tid = threadIdx.x, blk = blockIdx.x;
    int ex = block_exscan(bsum[tid], tid);      // global bucket base
    base_l[tid] = ex + H[tid * HSTR + blk];     // + this block's chunk offset
    rank[tid] = 0;
    __syncthreads();
    const uint4* col4 = reinterpret_cast<const uint4*>(col + blk * CHUNK2);
    const uint4* row4 = reinterpret_cast<const uint4*>(row + blk * CHUNK2);
    for (int i = tid; i < CHUNK2 / 4; i += 256) {
        uint4 c4 = col4[i];
        uint4 r4 = row4[i];
        #pragma unroll
        for (int e = 0; e < 4; ++e) {
            unsigned c = (e == 0) ? c4.x : (e == 1) ? c4.y : (e == 2) ? c4.z : c4.w;
            unsigned r = (e == 0) ? r4.x : (e == 1) ? r4.y : (e == 2) ? r4.z : r4.w;
            int bk = c >> 8;
            int rk = atomicAdd(&rank[bk], 1);
            packed[base_l[bk] + rk] = (r & 0xFFFF) | ((c & 0xFF) << 16);
        }
    }
}

// pass D: per-bucket CSR finalize: off/cnt per node + csr ushort rows.
__global__ __launch_bounds__(256) void k_csr(const unsigned int* __restrict__ packed,
                                             const int* __restrict__ bsum,
                                             int* __restrict__ off,
                                             int* __restrict__ cnt,
                                             unsigned short* __restrict__ csr) {
    __shared__ int exs[NBUK];
    __shared__ int ncnt[NBUK];
    __shared__ int nbase[NBUK];
    __shared__ int rk2[NBUK];
    const int tid = threadIdx.x, b = blockIdx.x;
    int ex = block_exscan(bsum[tid], tid);
    exs[tid] = ex;
    ncnt[tid] = 0;
    rk2[tid] = 0;
    __syncthreads();
    const int start = exs[b];
    const int size  = bsum[b];
    for (int i = tid; i < size; i += 256)
        atomicAdd(&ncnt[(packed[start + i] >> 16) & 0xFF], 1);
    __syncthreads();
    int v2  = ncnt[tid];
    int ex2 = block_exscan(v2, tid);
    const int node = b * NBUK + tid;
    off[node] = start + ex2;
    cnt[node] = v2;
    nbase[tid] = start + ex2;
    __syncthreads();
    for (int i = tid; i < size; i += 256) {
        unsigned u = packed[start + i];
        int ln = (u >> 16) & 0xFF;
        int rk = atomicAdd(&rk2[ln], 1);
        csr[nbase[ln] + rk] = (unsigned short)(u & 0xFFFF);
    }
}

// ---------------------------------------------------------------------------
// k_gemm: y[r][d] = fp16( (feat[r] . W[:,d]) * rsqrt(cnt[r]+1) )
__global__ __launch_bounds__(256) void k_gemm(const float* __restrict__ feat,
                                              const float* __restrict__ W,
                                              const int* __restrict__ cnt,
                                              __half* __restrict__ y) {
    __shared__ float feat_lds[64 * FS];
    __shared__ float W_lds[D * D];

    const int tid   = threadIdx.x;
    const int rbase = blockIdx.x * 64;

    {
        const float4* W4  = reinterpret_cast<const float4*>(W);
        float4*       Wl4 = reinterpret_cast<float4*>(W_lds);
        for (int i = tid; i < D * D / 4; i += 256) Wl4[i] = W4[i];
    }
    {
        const int k0 = (tid & 15) * 4;
        #pragma unroll
        for (int it = 0; it < 4; ++it) {
            int r  = it * 16 + (tid >> 4);
            int gr = rbase + r;
            float4 v = make_float4(0.f, 0.f, 0.f, 0.f);
            if (gr < NN) v = *reinterpret_cast<const float4*>(&feat[gr * D + k0]);
            *reinterpret_cast<float4*>(&feat_lds[r * FS + k0]) = v;
        }
    }
    __syncthreads();

    const int tx = tid & 15;
    const int ty = tid >> 4;

    float acc[4][4] = {};

    #pragma unroll 8
    for (int k = 0; k < D; ++k) {
        float4 w = *reinterpret_cast<const float4*>(&W_lds[k * D + tx * 4]);
        float f0 = feat_lds[(ty * 4 + 0) * FS + k];
        float f1 = feat_lds[(ty * 4 + 1) * FS + k];
        float f2 = feat_lds[(ty * 4 + 2) * FS + k];
        float f3 = feat_lds[(ty * 4 + 3) * FS + k];
        acc[0][0] = fmaf(f0, w.x, acc[0][0]); acc[0][1] = fmaf(f0, w.y, acc[0][1]);
        acc[0][2] = fmaf(f0, w.z, acc[0][2]); acc[0][3] = fmaf(f0, w.w, acc[0][3]);
        acc[1][0] = fmaf(f1, w.x, acc[1][0]); acc[1][1] = fmaf(f1, w.y, acc[1][1]);
        acc[1][2] = fmaf(f1, w.z, acc[1][2]); acc[1][3] = fmaf(f1, w.w, acc[1][3]);
        acc[2][0] = fmaf(f2, w.x, acc[2][0]); acc[2][1] = fmaf(f2, w.y, acc[2][1]);
        acc[2][2] = fmaf(f2, w.z, acc[2][2]); acc[2][3] = fmaf(f2, w.w, acc[2][3]);
        acc[3][0] = fmaf(f3, w.x, acc[3][0]); acc[3][1] = fmaf(f3, w.y, acc[3][1]);
        acc[3][2] = fmaf(f3, w.z, acc[3][2]); acc[3][3] = fmaf(f3, w.w, acc[3][3]);
    }

    #pragma unroll
    for (int i = 0; i < 4; ++i) {
        int gr = rbase + ty * 4 + i;
        if (gr < NN) {
            float s = rsqrtf((float)cnt[gr] + 1.0f);
            __half2 h0 = __floats2half2_rn(acc[i][0] * s, acc[i][1] * s);
            __half2 h1 = __floats2half2_rn(acc[i][2] * s, acc[i][3] * s);
            union { __half2 h[2]; uint2 u; } p;
            p.h[0] = h0; p.h[1] = h1;
            *reinterpret_cast<uint2*>(&y[gr * D + tx * 4]) = p.u;
        }
    }
}

// ---------------------------------------------------------------------------
// k_agg8: R10's proven structure + forced <=64 VGPR for 8 waves/SIMD.
//  - 8-lane group per node, 8 nodes/wave, lane owns 8 dims (no reduction).
//  - pre0..3 hold 32 edge ids; per 8-edge block all 8 row-gathers issue
//    unconditionally (safe index 0 when OOB) before mask-FMA accumulation.
//  - shfl guards wave-uniform (maxn) -> all 64 lanes active at every shfl.
//  - __launch_bounds__(256, 8): cap VGPR at 64 -> up to 32 waves/CU to hide
//    gather latency (live set ~58 VGPR, should not spill).
__global__ __launch_bounds__(256, 8) void k_agg8(const unsigned short* __restrict__ csr,
                                                 const int* __restrict__ off,
                                                 const int* __restrict__ cnt,
                                                 const __half* __restrict__ y,
                                                 const float* __restrict__ b,
                                                 float* __restrict__ out) {
    const int lane = threadIdx.x & 63;
    const int g    = lane >> 3;        // group 0..7 = node slot within wave
    const int l8   = lane & 7;         // dim block within the node's row
    const int wave = blockIdx.x * 4 + (threadIdx.x >> 6);
    const int c    = wave * 8 + g;
    const bool valid = (c < NN);

    const uint4* y16 = reinterpret_cast<const uint4*>(y);

    const int s = valid ? off[c] : 0;
    const int n = valid ? cnt[c] : 0;   // group-uniform

    // wave max of n
    int maxn = n;
    maxn = max(maxn, __shfl_xor(maxn, 8));
    maxn = max(maxn, __shfl_xor(maxn, 16));
    maxn = max(maxn, __shfl_xor(maxn, 32));

    // prefetch up to 32 neighbor ids per group (pre_k = edge l8 + 8k)
    int pre0 = (l8      < n) ? (int)csr[s + l8     ] : 0;
    int pre1 = (l8 + 8  < n) ? (int)csr[s + l8 + 8 ] : 0;
    int pre2 = (l8 + 16 < n) ? (int)csr[s + l8 + 16] : 0;
    int pre3 = (l8 + 24 < n) ? (int)csr[s + l8 + 24] : 0;

    float acc[8] = {0.f, 0.f, 0.f, 0.f, 0.f, 0.f, 0.f, 0.f};

    auto addm = [&](uint4 u, float m) {
        const __half2* h = reinterpret_cast<const __half2*>(&u);
        float2 f0 = __half22float2(h[0]);
        float2 f1 = __half22float2(h[1]);
        float2 f2 = __half22float2(h[2]);
        float2 f3 = __half22float2(h[3]);
        acc[0] = fmaf(m, f0.x, acc[0]); acc[1] = fmaf(m, f0.y, acc[1]);
        acc[2] = fmaf(m, f1.x, acc[2]); acc[3] = fmaf(m, f1.y, acc[3]);
        acc[4] = fmaf(m, f2.x, acc[4]); acc[5] = fmaf(m, f2.y, acc[5]);
        acc[6] = fmaf(m, f3.x, acc[6]); acc[7] = fmaf(m, f3.y, acc[7]);
    };

    // self-loop (safe index when invalid, masked to 0)
    {
        int cs = valid ? c : 0;
        addm(y16[cs * 8 + l8], valid ? 1.0f : 0.0f);
    }

    const int srcb = lane & 56;   // first lane of this group

    #pragma unroll
    for (int w = 0; w < 4; ++w) {
        if (w * 8 < maxn) {                       // wave-uniform guard
            const int pw = (w == 0) ? pre0 : (w == 1) ? pre1
                         : (w == 2) ? pre2 : pre3;
            uint4 u[8];
            float msk[8];
            #pragma unroll
            for (int e = 0; e < 8; ++e) {
                int r = __shfl(pw, srcb + e);     // all 64 lanes active
                u[e] = y16[r * 8 + l8];           // unconditional -> 8 in flight
                msk[e] = (w * 8 + e < n) ? 1.0f : 0.0f;
            }
            #pragma unroll
            for (int e = 0; e < 8; ++e) addm(u[e], msk[e]);
        }
    }

    // rare tail (deg > 32): group-divergent, no shfl -> safe
    for (int i = 32; i < n; ++i) {
        int r = (int)csr[s + i];
        addm(y16[r * 8 + l8], 1.0f);
    }

    if (valid) {
        float sc = rsqrtf((float)n + 1.0f);
        const float4* b4 = reinterpret_cast<const float4*>(b);
        float4 bb0 = b4[l8 * 2], bb1 = b4[l8 * 2 + 1];
        f32x4 o0, o1;
        o0.x = acc[0] * sc + bb0.x;  o0.y = acc[1] * sc + bb0.y;
        o0.z = acc[2] * sc + bb0.z;  o0.w = acc[3] * sc + bb0.w;
        o1.x = acc[4] * sc + bb1.x;  o1.y = acc[5] * sc + bb1.y;
        o1.z = acc[6] * sc + bb1.z;  o1.w = acc[7] * sc + bb1.w;
        f32x4* out4 = reinterpret_cast<f32x4*>(out);
        __builtin_nontemporal_store(o0, &out4[c * 16 + l8 * 2]);
        __builtin_nontemporal_store(o1, &out4[c * 16 + l8 * 2 + 1]);
    }
}

// ---------------------------------------------------------------------------
extern "C" void kernel_launch(void* const* d_in, const int* in_sizes, int n_in,
                              void* d_out, int out_size, void* d_ws, size_t ws_size,
                              hipStream_t stream) {
    const float* feat = (const float*)d_in[0];   // [NN, D]
    const float* W    = (const float*)d_in[1];   // [D, D]
    const float* b    = (const float*)d_in[2];   // [D]
    const int*   ei   = (const int*)d_in[3];     // [2, NE]
    const int*   row  = ei;                      // sources
    const int*   col  = ei + NE;                 // targets

    float* out = (float*)d_out;                  // [NN, D]

    // workspace layout (~13 MB)
    int*            H      = (int*)d_ws;                      // [256*HSTR]
    int*            bsum   = H + NBUK * HSTR;                 // [256] (pad 1024)
    int*            cnt    = bsum + 1024;                     // [65536]
    int*            off    = cnt + 65536;                     // [65536]
    unsigned int*   packed = (unsigned int*)(off + 65536);    // [NE]
    unsigned short* csr    = (unsigned short*)(packed + NE);  // [NE]
    __half*         y      = (__half*)(csr + NE);             // [NN*D], 16B-aligned

    k_hist  <<<NBLKS, 256, 0, stream>>>(col, H);
    k_scanA <<<NBUK,  256, 0, stream>>>(H, bsum);
    k_bucket<<<NBLKS, 256, 0, stream>>>(row, col, H, bsum, packed);
    k_csr   <<<NBUK,  256, 0, stream>>>(packed, bsum, off, cnt, csr);
    k_gemm  <<<(NN + 63) / 64, 256, 0, stream>>>(feat, W, cnt, y);
    k_agg8  <<<(NN + 31) / 32, 256, 0, stream>>>(csr, off, cnt, y, b, out);
}

// Round 14
// 57.617 us; speedup vs baseline: 1.0760x; 1.0045x over previous
//
#include <hip/hip_runtime.h>
#include <hip/hip_fp16.h>

#define NN 50000
#define NE 800000
#define D  64
#define NBUK  256
#define NBLKS 500            // sort chunks: 500 x 1600 = 800000 exactly
#define CHUNK2 1600          // multiple of 4 -> uint4 edge reads
#define HSTR  512            // H row stride (500 used, padded)
#define FS 68                // feat LDS stride (pad 64 -> 68)

typedef float __attribute__((ext_vector_type(4))) f32x4;

// ---------------------------------------------------------------------------
// block-wide exclusive scan of one int per thread (256 threads = 4 waves).
__device__ inline int block_exscan(int val, int tid) {
    __shared__ int wsum[4];
    int lane = tid & 63, w = tid >> 6;
    int v = val;
    #pragma unroll
    for (int d = 1; d < 64; d <<= 1) {
        int t = __shfl_up(v, d);
        if (lane >= d) v += t;
    }
    if (lane == 63) wsum[w] = v;
    __syncthreads();
    int base = 0;
    #pragma unroll
    for (int i = 0; i < 4; ++i) base += (i < w) ? wsum[i] : 0;
    __syncthreads();
    return base + v - val;   // exclusive
}

// ---------------------------------------------------------------------------
// pass A: per-block LDS histogram over buckets (col>>8); uint4 edge reads.
__global__ __launch_bounds__(256) void k_hist(const int* __restrict__ col,
                                              int* __restrict__ H) {
    __shared__ int h[NBUK];
    const int tid = threadIdx.x, blk = blockIdx.x;
    h[tid] = 0;
    __syncthreads();
    const uint4* col4 = reinterpret_cast<const uint4*>(col + blk * CHUNK2);
    for (int i = tid; i < CHUNK2 / 4; i += 256) {
        uint4 v = col4[i];
        atomicAdd(&h[v.x >> 8], 1);
        atomicAdd(&h[v.y >> 8], 1);
        atomicAdd(&h[v.z >> 8], 1);
        atomicAdd(&h[v.w >> 8], 1);
    }
    __syncthreads();
    H[tid * HSTR + blk] = h[tid];
}

// pass B: per-bucket exclusive scan over the 500 block entries.
__global__ __launch_bounds__(256) void k_scanA(int* __restrict__ H,
                                               int* __restrict__ bsum) {
    const int tid = threadIdx.x, bkt = blockIdx.x;
    int* Hb = H + bkt * HSTR;
    int v0 = 0, v1 = 0;
    if (tid < 250) { v0 = Hb[2 * tid]; v1 = Hb[2 * tid + 1]; }
    int sum = v0 + v1;
    int ex = block_exscan(sum, tid);
    if (tid < 250) { Hb[2 * tid] = ex; Hb[2 * tid + 1] = ex + v0; }
    if (tid == 255) bsum[bkt] = ex;   // tid 255 has sum=0 -> ex == grand total
}

// pass C: scatter edges into bucket segments as packed (row | (col&255)<<16)
__global__ __launch_bounds__(256) void k_bucket(const int* __restrict__ row,
                                                const int* __restrict__ col,
                                                const int* __restrict__ H,
                                                const int* __restrict__ bsum,
                                                unsigned int* __restrict__ packed) {
    __shared__ int base_l[NBUK];
    __shared__ int rank[NBUK];
    const int tid = threadIdx.x, blk = blockIdx.x;
    int ex = block_exscan(bsum[tid], tid);      // global bucket base
    base_l[tid] = ex + H[tid * HSTR + blk];     // + this block's chunk offset
    rank[tid] = 0;
    __syncthreads();
    const uint4* col4 = reinterpret_cast<const uint4*>(col + blk * CHUNK2);
    const uint4* row4 = reinterpret_cast<const uint4*>(row + blk * CHUNK2);
    for (int i = tid; i < CHUNK2 / 4; i += 256) {
        uint4 c4 = col4[i];
        uint4 r4 = row4[i];
        #pragma unroll
        for (int e = 0; e < 4; ++e) {
            unsigned c = (e == 0) ? c4.x : (e == 1) ? c4.y : (e == 2) ? c4.z : c4.w;
            unsigned r = (e == 0) ? r4.x : (e == 1) ? r4.y : (e == 2) ? r4.z : r4.w;
            int bk = c >> 8;
            int rk = atomicAdd(&rank[bk], 1);
            packed[base_l[bk] + rk] = (r & 0xFFFF) | ((c & 0xFF) << 16);
        }
    }
}

// pass D: per-bucket CSR finalize: off/cnt per node + csr ushort rows.
__global__ __launch_bounds__(256) void k_csr(const unsigned int* __restrict__ packed,
                                             const int* __restrict__ bsum,
                                             int* __restrict__ off,
                                             int* __restrict__ cnt,
                                             unsigned short* __restrict__ csr) {
    __shared__ int exs[NBUK];
    __shared__ int ncnt[NBUK];
    __shared__ int nbase[NBUK];
    __shared__ int rk2[NBUK];
    const int tid = threadIdx.x, b = blockIdx.x;
    int ex = block_exscan(bsum[tid], tid);
    exs[tid] = ex;
    ncnt[tid] = 0;
    rk2[tid] = 0;
    __syncthreads();
    const int start = exs[b];
    const int size  = bsum[b];
    for (int i = tid; i < size; i += 256)
        atomicAdd(&ncnt[(packed[start + i] >> 16) & 0xFF], 1);
    __syncthreads();
    int v2  = ncnt[tid];
    int ex2 = block_exscan(v2, tid);
    const int node = b * NBUK + tid;
    off[node] = start + ex2;
    cnt[node] = v2;
    nbase[tid] = start + ex2;
    __syncthreads();
    for (int i = tid; i < size; i += 256) {
        unsigned u = packed[start + i];
        int ln = (u >> 16) & 0xFF;
        int rk = atomicAdd(&rk2[ln], 1);
        csr[nbase[ln] + rk] = (unsigned short)(u & 0xFFFF);
    }
}

// ---------------------------------------------------------------------------
// k_gemm: y[r][d] = fp16( (feat[r] . W[:,d]) * rsqrt(cnt[r]+1) )
__global__ __launch_bounds__(256) void k_gemm(const float* __restrict__ feat,
                                              const float* __restrict__ W,
                                              const int* __restrict__ cnt,
                                              __half* __restrict__ y) {
    __shared__ float feat_lds[64 * FS];
    __shared__ float W_lds[D * D];

    const int tid   = threadIdx.x;
    const int rbase = blockIdx.x * 64;

    {
        const float4* W4  = reinterpret_cast<const float4*>(W);
        float4*       Wl4 = reinterpret_cast<float4*>(W_lds);
        for (int i = tid; i < D * D / 4; i += 256) Wl4[i] = W4[i];
    }
    {
        const int k0 = (tid & 15) * 4;
        #pragma unroll
        for (int it = 0; it < 4; ++it) {
            int r  = it * 16 + (tid >> 4);
            int gr = rbase + r;
            float4 v = make_float4(0.f, 0.f, 0.f, 0.f);
            if (gr < NN) v = *reinterpret_cast<const float4*>(&feat[gr * D + k0]);
            *reinterpret_cast<float4*>(&feat_lds[r * FS + k0]) = v;
        }
    }
    __syncthreads();

    const int tx = tid & 15;
    const int ty = tid >> 4;

    float acc[4][4] = {};

    #pragma unroll 8
    for (int k = 0; k < D; ++k) {
        float4 w = *reinterpret_cast<const float4*>(&W_lds[k * D + tx * 4]);
        float f0 = feat_lds[(ty * 4 + 0) * FS + k];
        float f1 = feat_lds[(ty * 4 + 1) * FS + k];
        float f2 = feat_lds[(ty * 4 + 2) * FS + k];
        float f3 = feat_lds[(ty * 4 + 3) * FS + k];
        acc[0][0] = fmaf(f0, w.x, acc[0][0]); acc[0][1] = fmaf(f0, w.y, acc[0][1]);
        acc[0][2] = fmaf(f0, w.z, acc[0][2]); acc[0][3] = fmaf(f0, w.w, acc[0][3]);
        acc[1][0] = fmaf(f1, w.x, acc[1][0]); acc[1][1] = fmaf(f1, w.y, acc[1][1]);
        acc[1][2] = fmaf(f1, w.z, acc[1][2]); acc[1][3] = fmaf(f1, w.w, acc[1][3]);
        acc[2][0] = fmaf(f2, w.x, acc[2][0]); acc[2][1] = fmaf(f2, w.y, acc[2][1]);
        acc[2][2] = fmaf(f2, w.z, acc[2][2]); acc[2][3] = fmaf(f2, w.w, acc[2][3]);
        acc[3][0] = fmaf(f3, w.x, acc[3][0]); acc[3][1] = fmaf(f3, w.y, acc[3][1]);
        acc[3][2] = fmaf(f3, w.z, acc[3][2]); acc[3][3] = fmaf(f3, w.w, acc[3][3]);
    }

    #pragma unroll
    for (int i = 0; i < 4; ++i) {
        int gr = rbase + ty * 4 + i;
        if (gr < NN) {
            float s = rsqrtf((float)cnt[gr] + 1.0f);
            __half2 h0 = __floats2half2_rn(acc[i][0] * s, acc[i][1] * s);
            __half2 h1 = __floats2half2_rn(acc[i][2] * s, acc[i][3] * s);
            union { __half2 h[2]; uint2 u; } p;
            p.h[0] = h0; p.h[1] = h1;
            *reinterpret_cast<uint2*>(&y[gr * D + tx * 4]) = p.u;
        }
    }
}

// ---------------------------------------------------------------------------
// k_agg8: R10 structure with GROUP-UNIFORM block guards (round-14 change).
//  - 8-lane group per node, 8 nodes/wave, lane owns 8 dims (no reduction).
//  - guard `if (w*8 < n)` diverges at GROUP granularity: groups with small n
//    skip whole 8-edge blocks -> masked lanes issue NO transactions, killing
//    the ~1.9x gather over-issue of the old wave-uniform maxn guard.
//  - shfl safety: source lane srcb+e is INSIDE the reader's own group, and a
//    group branches as a unit (n group-uniform), so every shfl source lane is
//    active whenever its readers are (no R7 inactive-source hazard).
//  - within an active block, all 8 row-gathers still issue before the
//    accumulates -> 8-deep MLP preserved. msk handles only the partial block.
__global__ __launch_bounds__(256, 8) void k_agg8(const unsigned short* __restrict__ csr,
                                                 const int* __restrict__ off,
                                                 const int* __restrict__ cnt,
                                                 const __half* __restrict__ y,
                                                 const float* __restrict__ b,
                                                 float* __restrict__ out) {
    const int lane = threadIdx.x & 63;
    const int g    = lane >> 3;        // group 0..7 = node slot within wave
    const int l8   = lane & 7;         // dim block within the node's row
    const int wave = blockIdx.x * 4 + (threadIdx.x >> 6);
    const int c    = wave * 8 + g;
    const bool valid = (c < NN);

    const uint4* y16 = reinterpret_cast<const uint4*>(y);

    const int s = valid ? off[c] : 0;
    const int n = valid ? cnt[c] : 0;   // group-uniform

    // prefetch up to 32 neighbor ids per group (pre_k = edge l8 + 8k)
    int pre0 = (l8      < n) ? (int)csr[s + l8     ] : 0;
    int pre1 = (l8 + 8  < n) ? (int)csr[s + l8 + 8 ] : 0;
    int pre2 = (l8 + 16 < n) ? (int)csr[s + l8 + 16] : 0;
    int pre3 = (l8 + 24 < n) ? (int)csr[s + l8 + 24] : 0;

    float acc[8] = {0.f, 0.f, 0.f, 0.f, 0.f, 0.f, 0.f, 0.f};

    auto addm = [&](uint4 u, float m) {
        const __half2* h = reinterpret_cast<const __half2*>(&u);
        float2 f0 = __half22float2(h[0]);
        float2 f1 = __half22float2(h[1]);
        float2 f2 = __half22float2(h[2]);
        float2 f3 = __half22float2(h[3]);
        acc[0] = fmaf(m, f0.x, acc[0]); acc[1] = fmaf(m, f0.y, acc[1]);
        acc[2] = fmaf(m, f1.x, acc[2]); acc[3] = fmaf(m, f1.y, acc[3]);
        acc[4] = fmaf(m, f2.x, acc[4]); acc[5] = fmaf(m, f2.y, acc[5]);
        acc[6] = fmaf(m, f3.x, acc[6]); acc[7] = fmaf(m, f3.y, acc[7]);
    };

    // self-loop (only valid groups execute)
    if (valid) addm(y16[c * 8 + l8], 1.0f);

    const int srcb = lane & 56;   // first lane of this group

    #pragma unroll
    for (int w = 0; w < 4; ++w) {
        if (w * 8 < n) {                          // GROUP-uniform guard
            const int pw = (w == 0) ? pre0 : (w == 1) ? pre1
                         : (w == 2) ? pre2 : pre3;
            uint4 u[8];
            float msk[8];
            #pragma unroll
            for (int e = 0; e < 8; ++e) {
                int r = __shfl(pw, srcb + e);     // source within own group
                u[e] = y16[r * 8 + l8];           // 8 in flight per group
                msk[e] = (w * 8 + e < n) ? 1.0f : 0.0f;
            }
            #pragma unroll
            for (int e = 0; e < 8; ++e) addm(u[e], msk[e]);
        }
    }

    // rare tail (deg > 32): group-divergent, no shfl -> safe
    for (int i = 32; i < n; ++i) {
        int r = (int)csr[s + i];
        addm(y16[r * 8 + l8], 1.0f);
    }

    if (valid) {
        float sc = rsqrtf((float)n + 1.0f);
        const float4* b4 = reinterpret_cast<const float4*>(b);
        float4 bb0 = b4[l8 * 2], bb1 = b4[l8 * 2 + 1];
        f32x4 o0, o1;
        o0.x = acc[0] * sc + bb0.x;  o0.y = acc[1] * sc + bb0.y;
        o0.z = acc[2] * sc + bb0.z;  o0.w = acc[3] * sc + bb0.w;
        o1.x = acc[4] * sc + bb1.x;  o1.y = acc[5] * sc + bb1.y;
        o1.z = acc[6] * sc + bb1.z;  o1.w = acc[7] * sc + bb1.w;
        f32x4* out4 = reinterpret_cast<f32x4*>(out);
        __builtin_nontemporal_store(o0, &out4[c * 16 + l8 * 2]);
        __builtin_nontemporal_store(o1, &out4[c * 16 + l8 * 2 + 1]);
    }
}

// ---------------------------------------------------------------------------
extern "C" void kernel_launch(void* const* d_in, const int* in_sizes, int n_in,
                              void* d_out, int out_size, void* d_ws, size_t ws_size,
                              hipStream_t stream) {
    const float* feat = (const float*)d_in[0];   // [NN, D]
    const float* W    = (const float*)d_in[1];   // [D, D]
    const float* b    = (const float*)d_in[2];   // [D]
    const int*   ei   = (const int*)d_in[3];     // [2, NE]
    const int*   row  = ei;                      // sources
    const int*   col  = ei + NE;                 // targets

    float* out = (float*)d_out;                  // [NN, D]

    // workspace layout (~13 MB)
    int*            H      = (int*)d_ws;                      // [256*HSTR]
    int*            bsum   = H + NBUK * HSTR;                 // [256] (pad 1024)
    int*            cnt    = bsum + 1024;                     // [65536]
    int*            off    = cnt + 65536;                     // [65536]
    unsigned int*   packed = (unsigned int*)(off + 65536);    // [NE]
    unsigned short* csr    = (unsigned short*)(packed + NE);  // [NE]
    __half*         y      = (__half*)(csr + NE);             // [NN*D], 16B-aligned

    k_hist  <<<NBLKS, 256, 0, stream>>>(col, H);
    k_scanA <<<NBUK,  256, 0, stream>>>(H, bsum);
    k_bucket<<<NBLKS, 256, 0, stream>>>(row, col, H, bsum, packed);
    k_csr   <<<NBUK,  256, 0, stream>>>(packed, bsum, off, cnt, csr);
    k_gemm  <<<(NN + 63) / 64, 256, 0, stream>>>(feat, W, cnt, y);
    k_agg8  <<<(NN + 31) / 32, 256, 0, stream>>>(csr, off, cnt, y, b, out);
}

// Round 15
// 53.866 us; speedup vs baseline: 1.1509x; 1.0696x over previous
//
#include <hip/hip_runtime.h>
#include <hip/hip_fp16.h>

#define NN 50000
#define NE 800000
#define D  64
#define NBUK  256
#define NBLKS 500            // sort chunks: 500 x 1600 = 800000 exactly
#define CHUNK2 1600          // multiple of 4 -> uint4 edge reads
#define HSTR  512            // H row stride (500 used, padded)
#define FS 68                // feat LDS stride (pad 64 -> 68)
#define GEMMB 782            // ceil(NN/64) gemm tiles
#define CAP 8192             // k_csr LDS edge capacity (bucket avg 4096, sd 64)

typedef float __attribute__((ext_vector_type(4))) f32x4;

// ---------------------------------------------------------------------------
// block-wide exclusive scan of one int per thread (256 threads = 4 waves).
__device__ inline int block_exscan(int val, int tid) {
    __shared__ int wsum[4];
    int lane = tid & 63, w = tid >> 6;
    int v = val;
    #pragma unroll
    for (int d = 1; d < 64; d <<= 1) {
        int t = __shfl_up(v, d);
        if (lane >= d) v += t;
    }
    if (lane == 63) wsum[w] = v;
    __syncthreads();
    int base = 0;
    #pragma unroll
    for (int i = 0; i < 4; ++i) base += (i < w) ? wsum[i] : 0;
    __syncthreads();
    return base + v - val;   // exclusive
}

// ---------------------------------------------------------------------------
// K1: fused hist + unscaled gemm (independent work, block-role split).
// blocks [0,NBLKS): LDS histogram of col>>8. blocks [NBLKS, NBLKS+GEMMB):
// y_raw[r][d] = fp16(feat[r].W[:,d])  (no deg scaling -> no cnt dependency).
__global__ __launch_bounds__(256) void k_hist_gemm(const int* __restrict__ col,
                                                   int* __restrict__ H,
                                                   const float* __restrict__ feat,
                                                   const float* __restrict__ W,
                                                   __half* __restrict__ y) {
    __shared__ float smem[64 * FS + D * D];   // 33.8 KB, shared by both roles
    const int tid = threadIdx.x;

    if (blockIdx.x < NBLKS) {
        // ---- histogram role ----
        int* h = reinterpret_cast<int*>(smem);
        const int blk = blockIdx.x;
        h[tid] = 0;
        __syncthreads();
        const uint4* col4 = reinterpret_cast<const uint4*>(col + blk * CHUNK2);
        for (int i = tid; i < CHUNK2 / 4; i += 256) {
            uint4 v = col4[i];
            atomicAdd(&h[v.x >> 8], 1);
            atomicAdd(&h[v.y >> 8], 1);
            atomicAdd(&h[v.z >> 8], 1);
            atomicAdd(&h[v.w >> 8], 1);
        }
        __syncthreads();
        H[tid * HSTR + blk] = h[tid];
        return;
    }

    // ---- gemm role ----
    float* feat_lds = smem;
    float* W_lds    = smem + 64 * FS;
    const int rbase = (blockIdx.x - NBLKS) * 64;

    {
        const float4* W4  = reinterpret_cast<const float4*>(W);
        float4*       Wl4 = reinterpret_cast<float4*>(W_lds);
        for (int i = tid; i < D * D / 4; i += 256) Wl4[i] = W4[i];
    }
    {
        const int k0 = (tid & 15) * 4;
        #pragma unroll
        for (int it = 0; it < 4; ++it) {
            int r  = it * 16 + (tid >> 4);
            int gr = rbase + r;
            float4 v = make_float4(0.f, 0.f, 0.f, 0.f);
            if (gr < NN) v = *reinterpret_cast<const float4*>(&feat[gr * D + k0]);
            *reinterpret_cast<float4*>(&feat_lds[r * FS + k0]) = v;
        }
    }
    __syncthreads();

    const int tx = tid & 15;
    const int ty = tid >> 4;

    float acc[4][4] = {};

    #pragma unroll 8
    for (int k = 0; k < D; ++k) {
        float4 w = *reinterpret_cast<const float4*>(&W_lds[k * D + tx * 4]);
        float f0 = feat_lds[(ty * 4 + 0) * FS + k];
        float f1 = feat_lds[(ty * 4 + 1) * FS + k];
        float f2 = feat_lds[(ty * 4 + 2) * FS + k];
        float f3 = feat_lds[(ty * 4 + 3) * FS + k];
        acc[0][0] = fmaf(f0, w.x, acc[0][0]); acc[0][1] = fmaf(f0, w.y, acc[0][1]);
        acc[0][2] = fmaf(f0, w.z, acc[0][2]); acc[0][3] = fmaf(f0, w.w, acc[0][3]);
        acc[1][0] = fmaf(f1, w.x, acc[1][0]); acc[1][1] = fmaf(f1, w.y, acc[1][1]);
        acc[1][2] = fmaf(f1, w.z, acc[1][2]); acc[1][3] = fmaf(f1, w.w, acc[1][3]);
        acc[2][0] = fmaf(f2, w.x, acc[2][0]); acc[2][1] = fmaf(f2, w.y, acc[2][1]);
        acc[2][2] = fmaf(f2, w.z, acc[2][2]); acc[2][3] = fmaf(f2, w.w, acc[2][3]);
        acc[3][0] = fmaf(f3, w.x, acc[3][0]); acc[3][1] = fmaf(f3, w.y, acc[3][1]);
        acc[3][2] = fmaf(f3, w.z, acc[3][2]); acc[3][3] = fmaf(f3, w.w, acc[3][3]);
    }

    #pragma unroll
    for (int i = 0; i < 4; ++i) {
        int gr = rbase + ty * 4 + i;
        if (gr < NN) {
            __half2 h0 = __floats2half2_rn(acc[i][0], acc[i][1]);
            __half2 h1 = __floats2half2_rn(acc[i][2], acc[i][3]);
            union { __half2 h[2]; uint2 u; } p;
            p.h[0] = h0; p.h[1] = h1;
            *reinterpret_cast<uint2*>(&y[gr * D + tx * 4]) = p.u;
        }
    }
}

// ---------------------------------------------------------------------------
// K2: per-bucket exclusive scan over the 500 block entries.
__global__ __launch_bounds__(256) void k_scanA(int* __restrict__ H,
                                               int* __restrict__ bsum) {
    const int tid = threadIdx.x, bkt = blockIdx.x;
    int* Hb = H + bkt * HSTR;
    int v0 = 0, v1 = 0;
    if (tid < 250) { v0 = Hb[2 * tid]; v1 = Hb[2 * tid + 1]; }
    int sum = v0 + v1;
    int ex = block_exscan(sum, tid);
    if (tid < 250) { Hb[2 * tid] = ex; Hb[2 * tid + 1] = ex + v0; }
    if (tid == 255) bsum[bkt] = ex;   // tid 255 has sum=0 -> ex == grand total
}

// ---------------------------------------------------------------------------
// K3: scatter edges into bucket segments as packed (row | (col&255)<<16)
__global__ __launch_bounds__(256) void k_bucket(const int* __restrict__ row,
                                                const int* __restrict__ col,
                                                const int* __restrict__ H,
                                                const int* __restrict__ bsum,
                                                unsigned int* __restrict__ packed) {
    __shared__ int base_l[NBUK];
    __shared__ int rank[NBUK];
    const int tid = threadIdx.x, blk = blockIdx.x;
    int ex = block_exscan(bsum[tid], tid);      // global bucket base
    base_l[tid] = ex + H[tid * HSTR + blk];     // + this block's chunk offset
    rank[tid] = 0;
    __syncthreads();
    const uint4* col4 = reinterpret_cast<const uint4*>(col + blk * CHUNK2);
    const uint4* row4 = reinterpret_cast<const uint4*>(row + blk * CHUNK2);
    for (int i = tid; i < CHUNK2 / 4; i += 256) {
        uint4 c4 = col4[i];
        uint4 r4 = row4[i];
        #pragma unroll
        for (int e = 0; e < 4; ++e) {
            unsigned c = (e == 0) ? c4.x : (e == 1) ? c4.y : (e == 2) ? c4.z : c4.w;
            unsigned r = (e == 0) ? r4.x : (e == 1) ? r4.y : (e == 2) ? r4.z : r4.w;
            int bk = c >> 8;
            int rk = atomicAdd(&rank[bk], 1);
            packed[base_l[bk] + rk] = (r & 0xFFFF) | ((c & 0xFF) << 16);
        }
    }
}

// ---------------------------------------------------------------------------
// K4: per-bucket CSR finalize, single global pass via LDS staging.
// Loads the bucket's packed edges into LDS once, counts+scans+scatters in
// LDS, then flushes csr LINEARLY (coalesced). Also emits dinv[] (fp32).
// Fallback to the 2-pass global path if a bucket exceeds CAP (never for
// this dataset: bucket size ~ Poisson(4096), CAP = 8192).
__global__ __launch_bounds__(256) void k_csr(const unsigned int* __restrict__ packed,
                                             const int* __restrict__ bsum,
                                             int* __restrict__ off,
                                             int* __restrict__ cnt,
                                             float* __restrict__ dinv,
                                             unsigned short* __restrict__ csr) {
    __shared__ unsigned pk[CAP];            // 32 KB
    __shared__ unsigned short lcsr[CAP];    // 16 KB
    __shared__ int ncnt[NBUK];
    __shared__ int nbase[NBUK];
    __shared__ int rk2[NBUK];
    __shared__ int sstart;
    const int tid = threadIdx.x, b = blockIdx.x;

    int ex = block_exscan(bsum[tid], tid);
    if (tid == b) sstart = ex;
    ncnt[tid] = 0;
    rk2[tid] = 0;
    __syncthreads();

    const int start = sstart;
    const int size  = bsum[b];

    if (size <= CAP) {
        // stage packed bucket in LDS (one global read pass)
        for (int i = tid; i < size; i += 256) pk[i] = packed[start + i];
        __syncthreads();
        for (int i = tid; i < size; i += 256)
            atomicAdd(&ncnt[(pk[i] >> 16) & 0xFF], 1);
        __syncthreads();
        int v2  = ncnt[tid];
        int ex2 = block_exscan(v2, tid);
        const int node = b * NBUK + tid;
        off[node]  = start + ex2;
        cnt[node]  = v2;
        dinv[node] = rsqrtf((float)v2 + 1.0f);
        nbase[tid] = ex2;                    // LOCAL base within bucket
        __syncthreads();
        for (int i = tid; i < size; i += 256) {
            unsigned u = pk[i];
            int ln = (u >> 16) & 0xFF;
            int rk = atomicAdd(&rk2[ln], 1);
            lcsr[nbase[ln] + rk] = (unsigned short)(u & 0xFFFF);
        }
        __syncthreads();
        // coalesced linear flush
        for (int i = tid; i < size; i += 256) csr[start + i] = lcsr[i];
    } else {
        // fallback: original 2-pass global path
        for (int i = tid; i < size; i += 256)
            atomicAdd(&ncnt[(packed[start + i] >> 16) & 0xFF], 1);
        __syncthreads();
        int v2  = ncnt[tid];
        int ex2 = block_exscan(v2, tid);
        const int node = b * NBUK + tid;
        off[node]  = start + ex2;
        cnt[node]  = v2;
        dinv[node] = rsqrtf((float)v2 + 1.0f);
        nbase[tid] = start + ex2;
        __syncthreads();
        for (int i = tid; i < size; i += 256) {
            unsigned u = packed[start + i];
            int ln = (u >> 16) & 0xFF;
            int rk = atomicAdd(&rk2[ln], 1);
            csr[nbase[ln] + rk] = (unsigned short)(u & 0xFFFF);
        }
    }
}

// ---------------------------------------------------------------------------
// K5: agg, R10 structure; dinv[r] folded into the mask multiplier (msk[e]
// becomes a gathered dinv instead of 1.0f -> zero extra FMAs; dinv loads are
// 8-lane-broadcast transactions, proven free by R14).
__global__ __launch_bounds__(256, 8) void k_agg8(const unsigned short* __restrict__ csr,
                                                 const int* __restrict__ off,
                                                 const int* __restrict__ cnt,
                                                 const float* __restrict__ dinv,
                                                 const __half* __restrict__ y,
                                                 const float* __restrict__ b,
                                                 float* __restrict__ out) {
    const int lane = threadIdx.x & 63;
    const int g    = lane >> 3;        // group 0..7 = node slot within wave
    const int l8   = lane & 7;         // dim block within the node's row
    const int wave = blockIdx.x * 4 + (threadIdx.x >> 6);
    const int c    = wave * 8 + g;
    const bool valid = (c < NN);

    const uint4* y16 = reinterpret_cast<const uint4*>(y);

    const int s = valid ? off[c] : 0;
    const int n = valid ? cnt[c] : 0;   // group-uniform
    const float dc = valid ? dinv[c] : 0.0f;

    // prefetch up to 32 neighbor ids per group (pre_k = edge l8 + 8k)
    int pre0 = (l8      < n) ? (int)csr[s + l8     ] : 0;
    int pre1 = (l8 + 8  < n) ? (int)csr[s + l8 + 8 ] : 0;
    int pre2 = (l8 + 16 < n) ? (int)csr[s + l8 + 16] : 0;
    int pre3 = (l8 + 24 < n) ? (int)csr[s + l8 + 24] : 0;

    float acc[8] = {0.f, 0.f, 0.f, 0.f, 0.f, 0.f, 0.f, 0.f};

    auto addm = [&](uint4 u, float m) {
        const __half2* h = reinterpret_cast<const __half2*>(&u);
        float2 f0 = __half22float2(h[0]);
        float2 f1 = __half22float2(h[1]);
        float2 f2 = __half22float2(h[2]);
        float2 f3 = __half22float2(h[3]);
        acc[0] = fmaf(m, f0.x, acc[0]); acc[1] = fmaf(m, f0.y, acc[1]);
        acc[2] = fmaf(m, f1.x, acc[2]); acc[3] = fmaf(m, f1.y, acc[3]);
        acc[4] = fmaf(m, f2.x, acc[4]); acc[5] = fmaf(m, f2.y, acc[5]);
        acc[6] = fmaf(m, f3.x, acc[6]); acc[7] = fmaf(m, f3.y, acc[7]);
    };

    // self-loop: weight dinv[c]
    if (valid) addm(y16[c * 8 + l8], dc);

    const int srcb = lane & 56;   // first lane of this group

    #pragma unroll
    for (int w = 0; w < 4; ++w) {
        if (w * 8 < n) {                          // GROUP-uniform guard
            const int pw = (w == 0) ? pre0 : (w == 1) ? pre1
                         : (w == 2) ? pre2 : pre3;
            uint4 u[8];
            float msk[8];
            #pragma unroll
            for (int e = 0; e < 8; ++e) {
                int r = __shfl(pw, srcb + e);     // source within own group
                u[e] = y16[r * 8 + l8];           // 8 in flight per group
                float dv = dinv[r];               // broadcast load (8 lanes same)
                msk[e] = (w * 8 + e < n) ? dv : 0.0f;
            }
            #pragma unroll
            for (int e = 0; e < 8; ++e) addm(u[e], msk[e]);
        }
    }

    // rare tail (deg > 32): group-divergent, no shfl -> safe
    for (int i = 32; i < n; ++i) {
        int r = (int)csr[s + i];
        addm(y16[r * 8 + l8], dinv[r]);
    }

    if (valid) {
        const float4* b4 = reinterpret_cast<const float4*>(b);
        float4 bb0 = b4[l8 * 2], bb1 = b4[l8 * 2 + 1];
        f32x4 o0, o1;
        o0.x = acc[0] * dc + bb0.x;  o0.y = acc[1] * dc + bb0.y;
        o0.z = acc[2] * dc + bb0.z;  o0.w = acc[3] * dc + bb0.w;
        o1.x = acc[4] * dc + bb1.x;  o1.y = acc[5] * dc + bb1.y;
        o1.z = acc[6] * dc + bb1.z;  o1.w = acc[7] * dc + bb1.w;
        f32x4* out4 = reinterpret_cast<f32x4*>(out);
        __builtin_nontemporal_store(o0, &out4[c * 16 + l8 * 2]);
        __builtin_nontemporal_store(o1, &out4[c * 16 + l8 * 2 + 1]);
    }
}

// ---------------------------------------------------------------------------
extern "C" void kernel_launch(void* const* d_in, const int* in_sizes, int n_in,
                              void* d_out, int out_size, void* d_ws, size_t ws_size,
                              hipStream_t stream) {
    const float* feat = (const float*)d_in[0];   // [NN, D]
    const float* W    = (const float*)d_in[1];   // [D, D]
    const float* b    = (const float*)d_in[2];   // [D]
    const int*   ei   = (const int*)d_in[3];     // [2, NE]
    const int*   row  = ei;                      // sources
    const int*   col  = ei + NE;                 // targets

    float* out = (float*)d_out;                  // [NN, D]

    // workspace layout (~13 MB)
    int*            H      = (int*)d_ws;                      // [256*HSTR]
    int*            bsum   = H + NBUK * HSTR;                 // [256] (pad 1024)
    int*            cnt    = bsum + 1024;                     // [65536]
    int*            off    = cnt + 65536;                     // [65536]
    float*          dinv   = (float*)(off + 65536);           // [65536]
    unsigned int*   packed = (unsigned int*)(dinv + 65536);   // [NE]
    unsigned short* csr    = (unsigned short*)(packed + NE);  // [NE]
    __half*         y      = (__half*)(csr + NE);             // [NN*D], 16B-aligned

    k_hist_gemm<<<NBLKS + GEMMB, 256, 0, stream>>>(col, H, feat, W, y);
    k_scanA    <<<NBUK,  256, 0, stream>>>(H, bsum);
    k_bucket   <<<NBLKS, 256, 0, stream>>>(row, col, H, bsum, packed);
    k_csr      <<<NBUK,  256, 0, stream>>>(packed, bsum, off, cnt, dinv, csr);
    k_agg8     <<<(NN + 31) / 32, 256, 0, stream>>>(csr, off, cnt, dinv, y, b, out);
}